// Round 10
// baseline (150.201 us; speedup 1.0000x reference)
//
#include <hip/hip_runtime.h>

// BatchWiseSimCLR: out = mean_b,i logsumexp_{j!=i}(cos(z_bi,z_bj)/T) - mean_r cos(x_r,xp_r)/T
// 2B=128 batch rows, MS=512 items/batch, D=256, T=0.5.

#define TWO_B   128
#define MS      512
#define DDIM    256
#define NROWS   32768          // TWO_B * K = 128*256
#define TEMP_INV 2.0f
#define EPSN     1e-8f
#define SQRT2   1.41421356237f

typedef __attribute__((ext_vector_type(8))) short  short8;   // 8 x bf16 (4 VGPRs)
typedef __attribute__((ext_vector_type(4))) float  f32x4;    // MFMA acc

__device__ __forceinline__ unsigned short f2bf(float f) {
  union { float f; unsigned u; } c; c.f = f;
  unsigned r = (c.u + 0x7FFFu + ((c.u >> 16) & 1u)) >> 16;   // RNE
  return (unsigned short)r;
}

// global_load_lds, 16B per lane; lds dest = wave-uniform base (+lane*16 by HW)
#define GLDS16(gp, lp)                                                         \
  __builtin_amdgcn_global_load_lds(                                            \
      (const __attribute__((address_space(1))) unsigned int*)(gp),             \
      (__attribute__((address_space(3))) unsigned int*)(lp), 16, 0, 0)

// ================= FAST PATH (needs ~34MB workspace) =================

// ---- K1f: row norms + write normalized bf16 zn (scaled by sqrt2) ----
// zn row (b*512+j): 256 ushorts, pre-swizzled in 16B granules:
// ushort u at offset u ^ ((j&7)<<3). sqrt2 fold: dot(zn_i,zn_j) = 2*cos = cos/T.
__global__ __launch_bounds__(256) void k_norm_f(
    const float* __restrict__ x, const float* __restrict__ xp,
    unsigned short* __restrict__ zn) {
  const int wid = threadIdx.x >> 6, lane = threadIdx.x & 63;
  #pragma unroll
  for (int itr = 0; itr < 4; ++itr) {
    const int r = itr * 8192 + blockIdx.x * 4 + wid;
    const int b = r & 127, i = r >> 7;          // r = i*128 + b
    const float4 a = ((const float4*)(x  + (size_t)r * DDIM))[lane];
    const float4 p = ((const float4*)(xp + (size_t)r * DDIM))[lane];
    float sxx = a.x*a.x + a.y*a.y + a.z*a.z + a.w*a.w;
    float spp = p.x*p.x + p.y*p.y + p.z*p.z + p.w*p.w;
    #pragma unroll
    for (int m = 1; m < 64; m <<= 1) {
      sxx += __shfl_xor(sxx, m);
      spp += __shfl_xor(spp, m);
    }
    const float inx = SQRT2 / fmaxf(sqrtf(sxx), EPSN);
    const float inp = SQRT2 / fmaxf(sqrtf(spp), EPSN);
    const int us = (lane * 4) ^ ((i & 7) << 3);
    ushort4 ox, op;
    ox.x = f2bf(a.x * inx); ox.y = f2bf(a.y * inx);
    ox.z = f2bf(a.z * inx); ox.w = f2bf(a.w * inx);
    op.x = f2bf(p.x * inp); op.y = f2bf(p.y * inp);
    op.z = f2bf(p.z * inp); op.w = f2bf(p.w * inp);
    *(ushort4*)(zn + ((size_t)(b * MS + i)       * DDIM) + us) = ox;
    *(ushort4*)(zn + ((size_t)(b * MS + 256 + i) * DDIM) + us) = op;
  }
}

// ---- K2f: gram + exp half-row-sums ----
// Grid (b=128, it=2, jh=2). Block: 4 waves, each owns 64 A-rows (av[4][8] in
// regs, direct from global zn). Per jt (64 B-rows staged in LDS, dbuf DMA),
// compute in TWO 32-col passes with acc[4][2] live (spill fix vs R9's
// acc[4][4]: 47us, WRITE_SIZE 66MB of scratch). Half-row sums -> rowsumh.
__device__ __forceinline__ void stage_b(const unsigned short* g,
                                        unsigned short* d, int wid, int lane) {
  #pragma unroll
  for (int s = 0; s < 8; ++s) {
    const int c = wid * 8 + s;                  // 1 KB chunks
    GLDS16(g + c * 512 + lane * 8, d + c * 512);
  }
}

__global__ __launch_bounds__(256, 2) void k_neg_f3(
    const unsigned short* __restrict__ zn,
    float* __restrict__ rowsumh, float* __restrict__ posn) {
  __shared__ __align__(16) unsigned short sh[2][64 * 256];   // 2 x 32 KB B dbuf
  const int b  = blockIdx.x;      // fastest: same-b blocks land on same XCD
  const int it = blockIdx.y;      // A half (256 rows)
  const int jh = blockIdx.z;      // B half (256 cols)
  const int lane = threadIdx.x & 63, wid = threadIdx.x >> 6;
  const int l15 = lane & 15, hi = lane >> 4;
  const int ri = hi << 2;                        // C/D row base within 16-tile

  // A-frags direct global->reg: wave owns rows it*256 + wid*64 .. +63
  short8 av[4][8];
  #pragma unroll
  for (int rb = 0; rb < 4; ++rb) {
    const int arow = it * 256 + wid * 64 + rb * 16 + l15;
    const unsigned short* gr = zn + (size_t)(b * MS + arow) * DDIM;
    const int swz = (arow & 7) << 3;
    #pragma unroll
    for (int kk = 0; kk < 8; ++kk) {
      const int col = kk * 32 + (hi << 3);
      av[rb][kk] = *(const short8*)(gr + (col ^ swz));
    }
  }

  // B pipeline: 4 tiles of 64 rows; tile jt in sh[jt&1]
  const unsigned short* gB = zn + (size_t)(b * MS + jh * 256) * DDIM;
  stage_b(gB, sh[0], wid, lane);                // tile 0
  stage_b(gB + 32768, sh[1], wid, lane);        // tile 1
  __syncthreads();                              // drains av + t0 + t1

  float rowacc[4][4] = {{0,0,0,0},{0,0,0,0},{0,0,0,0},{0,0,0,0}};
  float posl = 0.0f;

  #pragma unroll
  for (int jt = 0; jt < 4; ++jt) {
    // tile jt resident (tile jt+1's 8 chunks may stay in flight)
    if (jt == 3) asm volatile("s_waitcnt vmcnt(0)" ::: "memory");
    else         asm volatile("s_waitcnt vmcnt(8)" ::: "memory");
    __builtin_amdgcn_sched_barrier(0);
    __builtin_amdgcn_s_barrier();
    __builtin_amdgcn_sched_barrier(0);

    const unsigned short* Bsrc = sh[jt & 1];

    // two 32-col passes keep only acc[4][2] (32 VGPR) live
    #pragma unroll
    for (int nh = 0; nh < 2; ++nh) {
      f32x4 acc[4][2];
      #pragma unroll
      for (int rb = 0; rb < 4; ++rb) {
        acc[rb][0] = (f32x4){0, 0, 0, 0};
        acc[rb][1] = (f32x4){0, 0, 0, 0};
      }

      __builtin_amdgcn_s_setprio(1);
      #pragma unroll
      for (int kk = 0; kk < 8; ++kk) {
        const int col = kk * 32 + (hi << 3);
        #pragma unroll
        for (int ni = 0; ni < 2; ++ni) {
          const int br = nh * 32 + ni * 16 + l15;
          const short8 bv = *(const short8*)(Bsrc + br * 256 + (col ^ ((br & 7) << 3)));
          #pragma unroll
          for (int rb = 0; rb < 4; ++rb)
            acc[rb][ni] = __builtin_amdgcn_mfma_f32_16x16x32_bf16(av[rb][kk], bv, acc[rb][ni], 0, 0, 0);
        }
      }
      __builtin_amdgcn_s_setprio(0);

      // epilogue (reg-only): exp + diag/pos handling, accumulate row sums
      #pragma unroll
      for (int rb = 0; rb < 4; ++rb) {
        const int tb = it * 256 + wid * 64 + rb * 16;
        #pragma unroll
        for (int ni = 0; ni < 2; ++ni) {
          const int jtb = jh * 256 + jt * 64 + nh * 32 + ni * 16;
          const bool dtile = (jtb == tb);         // wave-uniform
          const bool ptile = (jtb == tb + 256);   // wave-uniform
          #pragma unroll
          for (int r2 = 0; r2 < 4; ++r2) {
            const float s = acc[rb][ni][r2];      // = cos/T (sqrt2 fold)
            float e = __expf(s);
            if (dtile && l15 == ri + r2) e = 0.0f;
            rowacc[rb][r2] += e;
            if (ptile && l15 == ri + r2) posl += s;
          }
        }
      }
    }

    __builtin_amdgcn_sched_barrier(0);
    __builtin_amdgcn_s_barrier();               // reads of sh[jt&1] done
    __builtin_amdgcn_sched_barrier(0);
    if (jt < 2) stage_b(gB + (size_t)(jt + 2) * 32768, sh[jt & 1], wid, lane);
  }

  // half-row sums: xor 1..8 completes the 16 cols within each lane-group;
  // lane l15==rb*4+r2 stores its group's row.
  #pragma unroll
  for (int rb = 0; rb < 4; ++rb)
    #pragma unroll
    for (int r2 = 0; r2 < 4; ++r2) {
      float v = rowacc[rb][r2];
      v += __shfl_xor(v, 1); v += __shfl_xor(v, 2);
      v += __shfl_xor(v, 4); v += __shfl_xor(v, 8);
      if (l15 == rb * 4 + r2) {
        const int row = it * 256 + wid * 64 + rb * 16 + ri + r2;
        rowsumh[((size_t)jh * TWO_B + b) * MS + row] = v;
      }
    }

  // posl: distinct per lane -> full butterfly, then 4-wave LDS combine
  #pragma unroll
  for (int m = 1; m < 64; m <<= 1) posl += __shfl_xor(posl, m);
  __shared__ float sp2[4];
  if (lane == 0) sp2[wid] = posl;
  __syncthreads();
  if (threadIdx.x == 0)
    posn[(blockIdx.z * 2 + blockIdx.y) * TWO_B + blockIdx.x] =
        sp2[0] + sp2[1] + sp2[2] + sp2[3];
}

// ---- K3f: combine halves, log, reduce (65536 rows + 512 pos partials) ----
__global__ __launch_bounds__(1024) void k_fin_f2(
    const float* __restrict__ rowsumh, const float* __restrict__ posn,
    float* __restrict__ out) {
  const int t = threadIdx.x, wid = t >> 6, lane = t & 63;
  float nacc = 0.0f;
  #pragma unroll 8
  for (int i = 0; i < 64; ++i) {
    const int r = i * 1024 + t;
    nacc += __logf(rowsumh[r] + rowsumh[65536 + r]);
  }
  float pacc = (t < 512) ? posn[t] : 0.0f;
  #pragma unroll
  for (int m = 1; m < 64; m <<= 1) {
    nacc += __shfl_xor(nacc, m);
    pacc += __shfl_xor(pacc, m);
  }
  __shared__ float sn[16], sp[16];
  if (lane == 0) { sn[wid] = nacc; sp[wid] = pacc; }
  __syncthreads();
  if (t == 0) {
    float nt = 0.0f, pt = 0.0f;
    #pragma unroll
    for (int i = 0; i < 16; ++i) { nt += sn[i]; pt += sp[i]; }
    out[0] = nt * (1.0f / 65536.0f) - pt * (1.0f / 32768.0f);
  }
}

// ================= FALLBACK PATH (R5, small workspace, verified) =================

__global__ __launch_bounds__(256) void k_norm(
    const float* __restrict__ x, const float* __restrict__ xp,
    float* __restrict__ invx, float* __restrict__ invp, float* __restrict__ posp) {
  const int wid = threadIdx.x >> 6, lane = threadIdx.x & 63;
  float posl = 0.0f;
  #pragma unroll
  for (int itr = 0; itr < 8; ++itr) {
    const int r = itr * 4096 + blockIdx.x * 4 + wid;
    const float4 a = ((const float4*)(x  + (size_t)r * DDIM))[lane];
    const float4 b = ((const float4*)(xp + (size_t)r * DDIM))[lane];
    float sxx = a.x*a.x + a.y*a.y + a.z*a.z + a.w*a.w;
    float spp = b.x*b.x + b.y*b.y + b.z*b.z + b.w*b.w;
    float sxp = a.x*b.x + a.y*b.y + a.z*b.z + a.w*b.w;
    #pragma unroll
    for (int m = 1; m < 64; m <<= 1) {
      sxx += __shfl_xor(sxx, m);
      spp += __shfl_xor(spp, m);
      sxp += __shfl_xor(sxp, m);
    }
    const float inx = 1.0f / fmaxf(sqrtf(sxx), EPSN);
    const float inp = 1.0f / fmaxf(sqrtf(spp), EPSN);
    if (lane == 0) {
      invx[r] = inx; invp[r] = inp;
      posl += sxp * inx * inp * TEMP_INV;
    }
  }
  __shared__ float cp[4];
  if (lane == 0) cp[wid] = posl;
  __syncthreads();
  if (threadIdx.x == 0) posp[blockIdx.x] = cp[0] + cp[1] + cp[2] + cp[3];
}

__device__ __forceinline__ void stage_tile(
    unsigned short* dst, const float* __restrict__ x, const float* __restrict__ xp,
    const float* __restrict__ invx, const float* __restrict__ invp, int b, int tilebase) {
  const int t = threadIdx.x;
  const bool isp = (tilebase >= 256);
  const float* src = isp ? xp : x;
  const float* inv = isp ? invp : invx;
  const int base_i = isp ? (tilebase - 256) : tilebase;
  #pragma unroll
  for (int s = 0; s < 16; ++s) {
    const int u   = s * 256 + t;
    const int row = u >> 6, c4 = u & 63;
    const int g   = (base_i + row) * TWO_B + b;
    const float4 v = *(const float4*)(src + (size_t)g * DDIM + c4 * 4);
    const float sc = inv[g];
    ushort4 o;
    o.x = f2bf(v.x * sc); o.y = f2bf(v.y * sc);
    o.z = f2bf(v.z * sc); o.w = f2bf(v.w * sc);
    *(ushort4*)(dst + row * 256 + ((c4 * 4) ^ ((row & 7) << 3))) = o;
  }
}

__global__ __launch_bounds__(256, 2) void k_neg(
    const float* __restrict__ x, const float* __restrict__ xp,
    const float* __restrict__ invx, const float* __restrict__ invp,
    float* __restrict__ negp) {
  __shared__ __align__(16) unsigned short As[64 * 256];
  __shared__ __align__(16) unsigned short Bs[64 * 256];
  const int b  = blockIdx.x;
  const int it = blockIdx.y;
  const int lane = threadIdx.x & 63, wid = threadIdx.x >> 6;

  stage_tile(As, x, xp, invx, invp, b, it * 64);
  float rowacc[4] = {0, 0, 0, 0};

  for (int jt = 0; jt < 8; ++jt) {
    __syncthreads();
    stage_tile(Bs, x, xp, invx, invp, b, jt * 64);
    __syncthreads();

    f32x4 acc[4] = {{0,0,0,0},{0,0,0,0},{0,0,0,0},{0,0,0,0}};
    #pragma unroll
    for (int kk = 0; kk < 8; ++kk) {
      const int col = kk * 32 + ((lane >> 4) << 3);
      const int ar  = wid * 16 + (lane & 15);
      const short8 av = *(const short8*)(As + ar * 256 + (col ^ ((ar & 7) << 3)));
      #pragma unroll
      for (int ni = 0; ni < 4; ++ni) {
        const int br = ni * 16 + (lane & 15);
        const short8 bv = *(const short8*)(Bs + br * 256 + (col ^ ((br & 7) << 3)));
        acc[ni] = __builtin_amdgcn_mfma_f32_16x16x32_bf16(av, bv, acc[ni], 0, 0, 0);
      }
    }
    const int igb = it * 64 + wid * 16 + ((lane >> 4) << 2);
    #pragma unroll
    for (int ni = 0; ni < 4; ++ni) {
      const int jg = jt * 64 + ni * 16 + (lane & 15);
      #pragma unroll
      for (int r2 = 0; r2 < 4; ++r2) {
        const float s = acc[ni][r2] * TEMP_INV;
        rowacc[r2] += ((igb + r2) == jg) ? 0.0f : __expf(s);
      }
    }
  }

  float partial = 0.0f;
  #pragma unroll
  for (int r2 = 0; r2 < 4; ++r2) {
    float v = rowacc[r2];
    v += __shfl_xor(v, 1); v += __shfl_xor(v, 2);
    v += __shfl_xor(v, 4); v += __shfl_xor(v, 8);
    partial += __logf(v);
  }
  partial += __shfl_xor(partial, 16);
  partial += __shfl_xor(partial, 32);

  __shared__ float sn[4];
  if (lane == 0) sn[wid] = partial;
  __syncthreads();
  if (threadIdx.x == 0)
    negp[blockIdx.y * TWO_B + blockIdx.x] = sn[0] + sn[1] + sn[2] + sn[3];
}

__global__ __launch_bounds__(256) void k_fin(
    const float* __restrict__ posp, const float* __restrict__ negp,
    float* __restrict__ out) {
  const int t = threadIdx.x, wid = t >> 6, lane = t & 63;
  const float4 p4 = ((const float4*)posp)[t];
  const float4 n4 = ((const float4*)negp)[t];
  float p = p4.x + p4.y + p4.z + p4.w;
  float n = n4.x + n4.y + n4.z + n4.w;
  #pragma unroll
  for (int m = 1; m < 64; m <<= 1) { p += __shfl_xor(p, m); n += __shfl_xor(n, m); }
  __shared__ float sp[4], sq[4];
  if (lane == 0) { sp[wid] = p; sq[wid] = n; }
  __syncthreads();
  if (t == 0) {
    const float pt = sp[0] + sp[1] + sp[2] + sp[3];
    const float nt = sq[0] + sq[1] + sq[2] + sq[3];
    out[0] = nt * (1.0f / 65536.0f) - pt * (1.0f / 32768.0f);
  }
}

extern "C" void kernel_launch(void* const* d_in, const int* in_sizes, int n_in,
                              void* d_out, int out_size, void* d_ws, size_t ws_size,
                              hipStream_t stream) {
  const float* x  = (const float*)d_in[0];
  const float* xp = (const float*)d_in[1];
  float* wsf = (float*)d_ws;
  float* out = (float*)d_out;

  // rowsumh 2*128*512 f32 (512KB) + posn 512 f32 + zn 32MB
  const size_t need_fast = (size_t)131584 * 4 + (size_t)65536 * DDIM * 2;
  if (ws_size >= need_fast) {
    float* rowsumh = wsf;                       // 131072
    float* posn = wsf + 131072;                 // 512
    unsigned short* zn = (unsigned short*)(wsf + 131584);
    k_norm_f<<<2048, 256, 0, stream>>>(x, xp, zn);
    k_neg_f3<<<dim3(TWO_B, 2, 2), 256, 0, stream>>>(zn, rowsumh, posn);
    k_fin_f2<<<1, 1024, 0, stream>>>(rowsumh, posn, out);
  } else {
    float* invx = wsf;
    float* invp = wsf + NROWS;
    float* posp = wsf + 2 * NROWS;
    float* negp = wsf + 2 * NROWS + 1024;
    k_norm<<<1024, 256, 0, stream>>>(x, xp, invx, invp, posp);
    k_neg<<<dim3(TWO_B, 8), 256, 0, stream>>>(x, xp, invx, invp, negp);
    k_fin<<<1, 256, 0, stream>>>(posp, negp, out);
  }
}

// Round 11
// 120.519 us; speedup vs baseline: 1.2463x; 1.2463x over previous
//
#include <hip/hip_runtime.h>

// BatchWiseSimCLR: out = mean_b,i logsumexp_{j!=i}(cos(z_bi,z_bj)/T) - mean_r cos(x_r,xp_r)/T
// 2B=128 batch rows, MS=512 items/batch, D=256, T=0.5.

#define TWO_B   128
#define MS      512
#define DDIM    256
#define NROWS   32768          // TWO_B * K = 128*256
#define TEMP_INV 2.0f
#define EPSN     1e-8f
#define SQRT2   1.41421356237f

typedef __attribute__((ext_vector_type(8))) short  short8;   // 8 x bf16 (4 VGPRs)
typedef __attribute__((ext_vector_type(4))) float  f32x4;    // MFMA acc

__device__ __forceinline__ unsigned short f2bf(float f) {
  union { float f; unsigned u; } c; c.f = f;
  unsigned r = (c.u + 0x7FFFu + ((c.u >> 16) & 1u)) >> 16;   // RNE
  return (unsigned short)r;
}

// global_load_lds, 16B per lane; lds dest = wave-uniform base (+lane*16 by HW)
#define GLDS16(gp, lp)                                                         \
  __builtin_amdgcn_global_load_lds(                                            \
      (const __attribute__((address_space(1))) unsigned int*)(gp),             \
      (__attribute__((address_space(3))) unsigned int*)(lp), 16, 0, 0)

// ================= FAST PATH (needs 32MB+4KB workspace) =================

// ---- K1f: row norms + write normalized bf16 zn (scaled by sqrt2) ----
// zn row (b*512+j): 256 ushorts, pre-swizzled in 16B granules:
// ushort u at offset u ^ ((j&7)<<3). sqrt2 fold: dot(zn_i,zn_j) = 2*cos = cos/T.
__global__ __launch_bounds__(256) void k_norm_f(
    const float* __restrict__ x, const float* __restrict__ xp,
    unsigned short* __restrict__ zn) {
  const int wid = threadIdx.x >> 6, lane = threadIdx.x & 63;
  #pragma unroll
  for (int itr = 0; itr < 4; ++itr) {
    const int r = itr * 8192 + blockIdx.x * 4 + wid;
    const int b = r & 127, i = r >> 7;          // r = i*128 + b
    const float4 a = ((const float4*)(x  + (size_t)r * DDIM))[lane];
    const float4 p = ((const float4*)(xp + (size_t)r * DDIM))[lane];
    float sxx = a.x*a.x + a.y*a.y + a.z*a.z + a.w*a.w;
    float spp = p.x*p.x + p.y*p.y + p.z*p.z + p.w*p.w;
    #pragma unroll
    for (int m = 1; m < 64; m <<= 1) {
      sxx += __shfl_xor(sxx, m);
      spp += __shfl_xor(spp, m);
    }
    const float inx = SQRT2 / fmaxf(sqrtf(sxx), EPSN);
    const float inp = SQRT2 / fmaxf(sqrtf(spp), EPSN);
    const int us = (lane * 4) ^ ((i & 7) << 3);
    ushort4 ox, op;
    ox.x = f2bf(a.x * inx); ox.y = f2bf(a.y * inx);
    ox.z = f2bf(a.z * inx); ox.w = f2bf(a.w * inx);
    op.x = f2bf(p.x * inp); op.y = f2bf(p.y * inp);
    op.z = f2bf(p.z * inp); op.w = f2bf(p.w * inp);
    *(ushort4*)(zn + ((size_t)(b * MS + i)       * DDIM) + us) = ox;
    *(ushort4*)(zn + ((size_t)(b * MS + 256 + i) * DDIM) + us) = op;
  }
}

// ---- K2f: gram + exp row-sums ----
// Grid (b=128, it=4). Block: 4 waves, each owns 32 A-rows (av[2][8]=64 VGPR,
// direct global->reg; NO av[4][8] -- that spilled in R9/R10, VGPR cap 128).
// B: 16 tiles of 32 rows, TRIPLE-buffered 16KB LDS (48KB total), prefetch
// depth 2, counted vmcnt(8). __launch_bounds__(256,3) -> 3 blocks/CU so
// barrier/DMA stalls are covered by a third block.
__device__ __forceinline__ void stage_b32(const unsigned short* g,
                                          unsigned short* d, int wid, int lane) {
  #pragma unroll
  for (int s = 0; s < 4; ++s) {
    const int c = wid * 4 + s;                  // 1 KB chunks, 16 per 16KB tile
    GLDS16(g + c * 512 + lane * 8, d + c * 512);
  }
}

__global__ __launch_bounds__(256, 3) void k_neg_f4(
    const unsigned short* __restrict__ zn,
    float* __restrict__ negp, float* __restrict__ posn) {
  __shared__ __align__(16) unsigned short sh[3][32 * 256];   // 3 x 16 KB B bufs
  const int b  = blockIdx.x;      // fastest: same-b blocks land on same XCD
  const int it = blockIdx.y;      // 0..3, 128-row A tile
  const int lane = threadIdx.x & 63, wid = threadIdx.x >> 6;
  const int l15 = lane & 15, hi = lane >> 4;
  const int ri = hi << 2;                        // C/D row base within 16-tile

  // A-frags direct global->reg: wave owns rows it*128 + wid*32 .. +31
  short8 av[2][8];
  #pragma unroll
  for (int rb = 0; rb < 2; ++rb) {
    const int arow = it * 128 + wid * 32 + rb * 16 + l15;
    const unsigned short* gr = zn + (size_t)(b * MS + arow) * DDIM;
    const int swz = (arow & 7) << 3;
    #pragma unroll
    for (int kk = 0; kk < 8; ++kk) {
      const int col = kk * 32 + (hi << 3);
      av[rb][kk] = *(const short8*)(gr + (col ^ swz));
    }
  }

  // B pipeline: 16 tiles of 32 rows; tile jt lives in sh[jt%3]
  const unsigned short* gB = zn + (size_t)b * MS * DDIM;
  stage_b32(gB,         sh[0], wid, lane);      // tile 0
  stage_b32(gB + 8192,  sh[1], wid, lane);      // tile 1
  stage_b32(gB + 16384, sh[2], wid, lane);      // tile 2

  float rowacc[2][4] = {{0,0,0,0},{0,0,0,0}};
  float posl = 0.0f;

  #pragma unroll
  for (int jt = 0; jt < 16; ++jt) {
    // wait: own chunks of tile jt done (up to 2 newer tiles in flight).
    // jt=0 also drains av-loads (older than t0) -- harmless, needed anyway.
    if (jt <= 13)      asm volatile("s_waitcnt vmcnt(8)" ::: "memory");
    else if (jt == 14) asm volatile("s_waitcnt vmcnt(4)" ::: "memory");
    else               asm volatile("s_waitcnt vmcnt(0)" ::: "memory");
    __builtin_amdgcn_sched_barrier(0);
    __builtin_amdgcn_s_barrier();               // tile jt fully in LDS
    __builtin_amdgcn_sched_barrier(0);

    const unsigned short* Bsrc = sh[jt % 3];
    f32x4 acc[2][2];
    acc[0][0] = (f32x4){0,0,0,0}; acc[0][1] = (f32x4){0,0,0,0};
    acc[1][0] = (f32x4){0,0,0,0}; acc[1][1] = (f32x4){0,0,0,0};

    __builtin_amdgcn_s_setprio(1);
    #pragma unroll
    for (int kk = 0; kk < 8; ++kk) {
      const int col = kk * 32 + (hi << 3);
      #pragma unroll
      for (int ni = 0; ni < 2; ++ni) {
        const int br = ni * 16 + l15;
        const short8 bv = *(const short8*)(Bsrc + br * 256 + (col ^ ((br & 7) << 3)));
        acc[0][ni] = __builtin_amdgcn_mfma_f32_16x16x32_bf16(av[0][kk], bv, acc[0][ni], 0, 0, 0);
        acc[1][ni] = __builtin_amdgcn_mfma_f32_16x16x32_bf16(av[1][kk], bv, acc[1][ni], 0, 0, 0);
      }
    }
    __builtin_amdgcn_s_setprio(0);

    __builtin_amdgcn_sched_barrier(0);
    __builtin_amdgcn_s_barrier();               // all reads of sh[jt%3] done
    __builtin_amdgcn_sched_barrier(0);
    if (jt < 13) stage_b32(gB + (size_t)(jt + 3) * 8192, sh[jt % 3], wid, lane);

    // epilogue (reg-only) AFTER stage-issue: overlaps DMA + other blocks
    #pragma unroll
    for (int rb = 0; rb < 2; ++rb) {
      const int tb = it * 128 + wid * 32 + rb * 16;
      #pragma unroll
      for (int ni = 0; ni < 2; ++ni) {
        const int jtb = jt * 32 + ni * 16;
        const bool dtile = (jtb == tb);         // wave-uniform
        const bool ptile = (jtb == tb + 256);   // wave-uniform
        #pragma unroll
        for (int r2 = 0; r2 < 4; ++r2) {
          const float s = acc[rb][ni][r2];      // = cos/T (sqrt2 fold)
          float e = __expf(s);
          if (dtile && l15 == ri + r2) e = 0.0f;
          rowacc[rb][r2] += e;
          if (ptile && l15 == ri + r2) posl += s;
        }
      }
    }
  }

  // full row sums within each 16-lane group (block covers all 512 cols),
  // then one log per row; xor16/32 combines one representative per group.
  float partial = 0.0f;
  #pragma unroll
  for (int rb = 0; rb < 2; ++rb)
    #pragma unroll
    for (int r2 = 0; r2 < 4; ++r2) {
      float v = rowacc[rb][r2];
      v += __shfl_xor(v, 1); v += __shfl_xor(v, 2);
      v += __shfl_xor(v, 4); v += __shfl_xor(v, 8);
      partial += __logf(v);
    }
  partial += __shfl_xor(partial, 16);
  partial += __shfl_xor(partial, 32);
  // posl: distinct contributions per lane -> full butterfly
  #pragma unroll
  for (int m = 1; m < 64; m <<= 1) posl += __shfl_xor(posl, m);

  __shared__ float sn[4], sp2[4];
  if (lane == 0) { sn[wid] = partial; sp2[wid] = posl; }
  __syncthreads();
  if (threadIdx.x == 0) {
    const int bid = blockIdx.y * TWO_B + blockIdx.x;
    negp[bid] = sn[0] + sn[1] + sn[2] + sn[3];
    posn[bid] = sp2[0] + sp2[1] + sp2[2] + sp2[3];
  }
}

// ---- K3f: reduce the two 512-entry partial arrays ----
__global__ __launch_bounds__(256) void k_fin_f(
    const float* __restrict__ posn, const float* __restrict__ negp,
    float* __restrict__ out) {
  const int t = threadIdx.x, wid = t >> 6, lane = t & 63;
  float p = posn[t] + posn[t + 256];
  float n = negp[t] + negp[t + 256];
  #pragma unroll
  for (int m = 1; m < 64; m <<= 1) { p += __shfl_xor(p, m); n += __shfl_xor(n, m); }
  __shared__ float sp[4], sq[4];
  if (lane == 0) { sp[wid] = p; sq[wid] = n; }
  __syncthreads();
  if (t == 0) {
    const float pt = sp[0] + sp[1] + sp[2] + sp[3];
    const float nt = sq[0] + sq[1] + sq[2] + sq[3];
    out[0] = nt * (1.0f / 65536.0f) - pt * (1.0f / 32768.0f);
  }
}

// ================= FALLBACK PATH (R5, small workspace, verified) =================

__global__ __launch_bounds__(256) void k_norm(
    const float* __restrict__ x, const float* __restrict__ xp,
    float* __restrict__ invx, float* __restrict__ invp, float* __restrict__ posp) {
  const int wid = threadIdx.x >> 6, lane = threadIdx.x & 63;
  float posl = 0.0f;
  #pragma unroll
  for (int itr = 0; itr < 8; ++itr) {
    const int r = itr * 4096 + blockIdx.x * 4 + wid;
    const float4 a = ((const float4*)(x  + (size_t)r * DDIM))[lane];
    const float4 b = ((const float4*)(xp + (size_t)r * DDIM))[lane];
    float sxx = a.x*a.x + a.y*a.y + a.z*a.z + a.w*a.w;
    float spp = b.x*b.x + b.y*b.y + b.z*b.z + b.w*b.w;
    float sxp = a.x*b.x + a.y*b.y + a.z*b.z + a.w*b.w;
    #pragma unroll
    for (int m = 1; m < 64; m <<= 1) {
      sxx += __shfl_xor(sxx, m);
      spp += __shfl_xor(spp, m);
      sxp += __shfl_xor(sxp, m);
    }
    const float inx = 1.0f / fmaxf(sqrtf(sxx), EPSN);
    const float inp = 1.0f / fmaxf(sqrtf(spp), EPSN);
    if (lane == 0) {
      invx[r] = inx; invp[r] = inp;
      posl += sxp * inx * inp * TEMP_INV;
    }
  }
  __shared__ float cp[4];
  if (lane == 0) cp[wid] = posl;
  __syncthreads();
  if (threadIdx.x == 0) posp[blockIdx.x] = cp[0] + cp[1] + cp[2] + cp[3];
}

__device__ __forceinline__ void stage_tile(
    unsigned short* dst, const float* __restrict__ x, const float* __restrict__ xp,
    const float* __restrict__ invx, const float* __restrict__ invp, int b, int tilebase) {
  const int t = threadIdx.x;
  const bool isp = (tilebase >= 256);
  const float* src = isp ? xp : x;
  const float* inv = isp ? invp : invx;
  const int base_i = isp ? (tilebase - 256) : tilebase;
  #pragma unroll
  for (int s = 0; s < 16; ++s) {
    const int u   = s * 256 + t;
    const int row = u >> 6, c4 = u & 63;
    const int g   = (base_i + row) * TWO_B + b;
    const float4 v = *(const float4*)(src + (size_t)g * DDIM + c4 * 4);
    const float sc = inv[g];
    ushort4 o;
    o.x = f2bf(v.x * sc); o.y = f2bf(v.y * sc);
    o.z = f2bf(v.z * sc); o.w = f2bf(v.w * sc);
    *(ushort4*)(dst + row * 256 + ((c4 * 4) ^ ((row & 7) << 3))) = o;
  }
}

__global__ __launch_bounds__(256, 2) void k_neg(
    const float* __restrict__ x, const float* __restrict__ xp,
    const float* __restrict__ invx, const float* __restrict__ invp,
    float* __restrict__ negp) {
  __shared__ __align__(16) unsigned short As[64 * 256];
  __shared__ __align__(16) unsigned short Bs[64 * 256];
  const int b  = blockIdx.x;
  const int it = blockIdx.y;
  const int lane = threadIdx.x & 63, wid = threadIdx.x >> 6;

  stage_tile(As, x, xp, invx, invp, b, it * 64);
  float rowacc[4] = {0, 0, 0, 0};

  for (int jt = 0; jt < 8; ++jt) {
    __syncthreads();
    stage_tile(Bs, x, xp, invx, invp, b, jt * 64);
    __syncthreads();

    f32x4 acc[4] = {{0,0,0,0},{0,0,0,0},{0,0,0,0},{0,0,0,0}};
    #pragma unroll
    for (int kk = 0; kk < 8; ++kk) {
      const int col = kk * 32 + ((lane >> 4) << 3);
      const int ar  = wid * 16 + (lane & 15);
      const short8 av = *(const short8*)(As + ar * 256 + (col ^ ((ar & 7) << 3)));
      #pragma unroll
      for (int ni = 0; ni < 4; ++ni) {
        const int br = ni * 16 + (lane & 15);
        const short8 bv = *(const short8*)(Bs + br * 256 + (col ^ ((br & 7) << 3)));
        acc[ni] = __builtin_amdgcn_mfma_f32_16x16x32_bf16(av, bv, acc[ni], 0, 0, 0);
      }
    }
    const int igb = it * 64 + wid * 16 + ((lane >> 4) << 2);
    #pragma unroll
    for (int ni = 0; ni < 4; ++ni) {
      const int jg = jt * 64 + ni * 16 + (lane & 15);
      #pragma unroll
      for (int r2 = 0; r2 < 4; ++r2) {
        const float s = acc[ni][r2] * TEMP_INV;
        rowacc[r2] += ((igb + r2) == jg) ? 0.0f : __expf(s);
      }
    }
  }

  float partial = 0.0f;
  #pragma unroll
  for (int r2 = 0; r2 < 4; ++r2) {
    float v = rowacc[r2];
    v += __shfl_xor(v, 1); v += __shfl_xor(v, 2);
    v += __shfl_xor(v, 4); v += __shfl_xor(v, 8);
    partial += __logf(v);
  }
  partial += __shfl_xor(partial, 16);
  partial += __shfl_xor(partial, 32);

  __shared__ float sn[4];
  if (lane == 0) sn[wid] = partial;
  __syncthreads();
  if (threadIdx.x == 0)
    negp[blockIdx.y * TWO_B + blockIdx.x] = sn[0] + sn[1] + sn[2] + sn[3];
}

__global__ __launch_bounds__(256) void k_fin(
    const float* __restrict__ posp, const float* __restrict__ negp,
    float* __restrict__ out) {
  const int t = threadIdx.x, wid = t >> 6, lane = t & 63;
  const float4 p4 = ((const float4*)posp)[t];
  const float4 n4 = ((const float4*)negp)[t];
  float p = p4.x + p4.y + p4.z + p4.w;
  float n = n4.x + n4.y + n4.z + n4.w;
  #pragma unroll
  for (int m = 1; m < 64; m <<= 1) { p += __shfl_xor(p, m); n += __shfl_xor(n, m); }
  __shared__ float sp[4], sq[4];
  if (lane == 0) { sp[wid] = p; sq[wid] = n; }
  __syncthreads();
  if (t == 0) {
    const float pt = sp[0] + sp[1] + sp[2] + sp[3];
    const float nt = sq[0] + sq[1] + sq[2] + sq[3];
    out[0] = nt * (1.0f / 65536.0f) - pt * (1.0f / 32768.0f);
  }
}

extern "C" void kernel_launch(void* const* d_in, const int* in_sizes, int n_in,
                              void* d_out, int out_size, void* d_ws, size_t ws_size,
                              hipStream_t stream) {
  const float* x  = (const float*)d_in[0];
  const float* xp = (const float*)d_in[1];
  float* wsf = (float*)d_ws;
  float* out = (float*)d_out;

  const size_t need_fast = 4096 + (size_t)65536 * DDIM * 2;   // partials + 32MB zn
  if (ws_size >= need_fast) {
    float* negp = wsf;                        // 512
    float* posn = wsf + 512;                  // 512
    unsigned short* zn = (unsigned short*)(wsf + 1024);
    k_norm_f<<<2048, 256, 0, stream>>>(x, xp, zn);
    k_neg_f4<<<dim3(TWO_B, 4), 256, 0, stream>>>(zn, negp, posn);
    k_fin_f<<<1, 256, 0, stream>>>(posn, negp, out);
  } else {
    float* invx = wsf;
    float* invp = wsf + NROWS;
    float* posp = wsf + 2 * NROWS;
    float* negp = wsf + 2 * NROWS + 1024;
    k_norm<<<1024, 256, 0, stream>>>(x, xp, invx, invp, posp);
    k_neg<<<dim3(TWO_B, 8), 256, 0, stream>>>(x, xp, invx, invp, negp);
    k_fin<<<1, 256, 0, stream>>>(posp, negp, out);
  }
}